// Round 3
// baseline (1951.866 us; speedup 1.0000x reference)
//
#include <hip/hip_runtime.h>
#include <cmath>

// CustomRNNCell: h_{t+1} = tanh(h_t @ W_h^T + b_h + x_t @ W_x^T + b_x)
// B=64, T=512, H=I=1024. Output: h_final [64,1024] fp32.
//
// Phase 1: xp[t][b][j] = x @ W_x^T + (b_x + b_h)   (bf16 MFMA GEMM, fp32 out)
// Phase 2 (R7): R6 flag protocol + 32-j-per-wave, W in REGISTERS.
//   - 128 blocks x 64 threads (1 wave): 4 batch-groups x 32 j-blocks (32 j).
//   - W_h slice (32 rows) held in 256 VGPRs (64 x s16x8 A-fragments), loaded
//     once. NO LDS in the scan at all: no ds_read, no bank conflicts.
//   - h loaded per step as 32 x global_load_dwordx4 sc0 sc1 (coherent IF
//     reads), 4 groups of 8 with counted vmcnt(24/16/8/0)+sched_barrier(0)
//     so MFMA of group g overlaps the load stream of groups g+1..
//   - Each 32 KB h fetch now feeds 2 C-tiles (32 j): per-step IF burst
//     halves vs R6 (4 MB vs 8 MB aggregate).
//   - Ring layout, 2-slot parity, flag-after-vmcnt(0) protocol: identical to
//     validated R6 (producer u64 idx = (jb*4+n*2+(q>>1))*32+m*2+(q&1)).

#define Bsz 64
#define Tsz 512
#define Hsz 1024

typedef float  f32x4 __attribute__((ext_vector_type(4)));
typedef short  s16x8 __attribute__((ext_vector_type(8)));

__device__ __forceinline__ unsigned short f2bf(float f) {
  unsigned u = __float_as_uint(f);
  u += 0x7fff + ((u >> 16) & 1);   // round-to-nearest-even (finite inputs)
  return (unsigned short)(u >> 16);
}

__device__ __forceinline__ void pack8(unsigned short* d, float4 v0, float4 v1) {
  d[0] = f2bf(v0.x); d[1] = f2bf(v0.y); d[2] = f2bf(v0.z); d[3] = f2bf(v0.w);
  d[4] = f2bf(v1.x); d[5] = f2bf(v1.y); d[6] = f2bf(v1.z); d[7] = f2bf(v1.w);
}

__device__ __forceinline__ float fast_tanh(float x) {
  float e = __expf(2.0f * x);
  return 1.0f - 2.0f / (e + 1.0f);
}

// ---------------- Phase 1: xp GEMM (unchanged, validated) ----------------
__global__ __launch_bounds__(256) void xp_gemm_kernel(
    const float* __restrict__ x, const float* __restrict__ Wx,
    const float* __restrict__ bx, const float* __restrict__ bh,
    float* __restrict__ xp) {
  __shared__ unsigned short Al[64 * 32];
  __shared__ unsigned short Bl[64 * 32];

  const int tid  = threadIdx.x;
  const int w    = tid >> 6;
  const int lane = tid & 63;
  const int m    = lane & 15;
  const int q    = lane >> 4;
  const int row0 = blockIdx.x * 64;   // flattened (b*T + t) row base
  const int col0 = blockIdx.y * 64;   // hidden col base

  f32x4 acc[4];
#pragma unroll
  for (int i = 0; i < 4; ++i) acc[i] = (f32x4){0.f, 0.f, 0.f, 0.f};

  const int sr = tid >> 2;
  const int sc = tid & 3;
  const int sw = sc ^ ((sr >> 1) & 3);

  for (int kt = 0; kt < 32; ++kt) {
    const int k0 = kt * 32 + sc * 8;
    {
      const float* p = x + (size_t)(row0 + sr) * 1024 + k0;
      pack8(&Al[sr * 32 + sw * 8], *(const float4*)p, *(const float4*)(p + 4));
    }
    {
      const float* p = Wx + (size_t)(col0 + sr) * 1024 + k0;
      pack8(&Bl[sr * 32 + sw * 8], *(const float4*)p, *(const float4*)(p + 4));
    }
    __syncthreads();
    const int arow = w * 16 + m;
    s16x8 a = *(const s16x8*)&Al[arow * 32 + ((q ^ ((arow >> 1) & 3)) << 3)];
#pragma unroll
    for (int nt = 0; nt < 4; ++nt) {
      const int nrow = nt * 16 + m;
      s16x8 b = *(const s16x8*)&Bl[nrow * 32 + ((q ^ ((nrow >> 1) & 3)) << 3)];
      acc[nt] = __builtin_amdgcn_mfma_f32_16x16x32_bf16(a, b, acc[nt], 0, 0, 0);
    }
    __syncthreads();
  }

#pragma unroll
  for (int nt = 0; nt < 4; ++nt) {
    const int col  = col0 + nt * 16 + m;
    const float bias = bx[col] + bh[col];
#pragma unroll
    for (int r = 0; r < 4; ++r) {
      const int rowg = row0 + w * 16 + q * 4 + r;  // = b*512 + t
      const int b = rowg >> 9;
      const int t = rowg & 511;
      xp[(size_t)t * (Bsz * Hsz) + b * Hsz + col] = acc[nt][r] + bias;
    }
  }
}

// ---------------- Phase 2: W-in-regs flag-gated scan ----------------
// Ring (bf16 units): slot[2] x group[4] x [(k>>3)*128 + b*8 + (k&7)],
// k = hidden 0..1023, b = batch-local 0..15.
// Slot stride 16384 u64 (128 KB), group stride 4096 u64 (32 KB).
// Consumer frag kk, lane(m,q): bytes kk*1024 + q*256 + m*16 (16 B = s16x8).
// Producer wave jb, tile n, lane(m,q): u64 idx (jb*4+n*2+(q>>1))*32+m*2+(q&1),
// hv[0..3] packed low->high.

#define HLOAD(D, g)                                                           \
  do {                                                                        \
    _Pragma("unroll")                                                         \
    for (int f_ = 0; f_ < 8; ++f_) {                                          \
      unsigned long long a_ = rb64 + (unsigned long long)(((g) * 8 + f_) * 1024); \
      asm volatile("global_load_dwordx4 %0, %1, off sc0 sc1"                  \
                   : "=v"(D[f_]) : "v"(a_) : "memory");                       \
    }                                                                         \
  } while (0)

#define HMFMA(D, g)                                                           \
  do {                                                                        \
    _Pragma("unroll")                                                         \
    for (int f_ = 0; f_ < 8; ++f_) {                                          \
      const int kk_ = (g) * 8 + f_;                                           \
      union { uint4 u; s16x8 v; } hb_; hb_.u = D[f_];                         \
      if (kk_ & 1) {                                                          \
        acc01 = __builtin_amdgcn_mfma_f32_16x16x32_bf16(wreg0[kk_], hb_.v, acc01, 0, 0, 0); \
        acc11 = __builtin_amdgcn_mfma_f32_16x16x32_bf16(wreg1[kk_], hb_.v, acc11, 0, 0, 0); \
      } else {                                                                \
        acc00 = __builtin_amdgcn_mfma_f32_16x16x32_bf16(wreg0[kk_], hb_.v, acc00, 0, 0, 0); \
        acc10 = __builtin_amdgcn_mfma_f32_16x16x32_bf16(wreg1[kk_], hb_.v, acc10, 0, 0, 0); \
      }                                                                       \
    }                                                                         \
  } while (0)

__global__ __launch_bounds__(64, 1) void rnn_scan_kernel(
    const float* __restrict__ Wh, const float* __restrict__ xp,
    float* __restrict__ out,
    unsigned long long* __restrict__ ring, unsigned* __restrict__ flags) {
  const int lane = threadIdx.x & 63;
  const int m    = lane & 15;       // batch-local (B-frag col / C col)
  const int q    = lane >> 4;
  const int gb   = blockIdx.x >> 5; // 0..3  batch group
  const int jb   = blockIdx.x & 31; // 0..31 j-block (32 output cols each)
  const int j0   = jb * 32;
  const int rb   = gb * 16;

  // W_h rows j0..j0+31 -> 256 VGPRs. A-frag (16x16x32): lane(m,q) holds
  // A[row=m][k = kk*32 + q*8 .. +7]; tile n rows are j0+n*16+m.
  s16x8 wreg0[32], wreg1[32];
#pragma unroll
  for (int kk = 0; kk < 32; ++kk) {
    const float* p0 = Wh + (size_t)(j0 + m) * 1024 + kk * 32 + q * 8;
    const float* p1 = Wh + (size_t)(j0 + 16 + m) * 1024 + kk * 32 + q * 8;
    float4 a0 = *(const float4*)p0, b0 = *(const float4*)(p0 + 4);
    float4 a1 = *(const float4*)p1, b1 = *(const float4*)(p1 + 4);
    s16x8 w0, w1;
    w0[0]=f2bf(a0.x); w0[1]=f2bf(a0.y); w0[2]=f2bf(a0.z); w0[3]=f2bf(a0.w);
    w0[4]=f2bf(b0.x); w0[5]=f2bf(b0.y); w0[6]=f2bf(b0.z); w0[7]=f2bf(b0.w);
    w1[0]=f2bf(a1.x); w1[1]=f2bf(a1.y); w1[2]=f2bf(a1.z); w1[3]=f2bf(a1.w);
    w1[4]=f2bf(b1.x); w1[5]=f2bf(b1.y); w1[6]=f2bf(b1.z); w1[7]=f2bf(b1.w);
    wreg0[kk] = w0; wreg1[kk] = w1;
  }

  unsigned* myflag = flags + (gb * 32 + jb) * 16;
  const unsigned* pollflag = flags + (gb * 32 + (lane & 31)) * 16;

  unsigned long long* const grp = ring + (size_t)gb * 4096;
  const int prod0 = (jb * 4 + 0 + (q >> 1)) * 32 + m * 2 + (q & 1);
  const int prod1 = (jb * 4 + 2 + (q >> 1)) * 32 + m * 2 + (q & 1);
  const int cons_byte = q * 256 + m * 16;

  for (int t = 0; t < Tsz; ++t) {
    // xp_t for (b = rb+m, j = j0 + n*16 + q*4 + r) — independent loads
    const float* xpt =
        xp + (size_t)t * (Bsz * Hsz) + (size_t)(rb + m) * Hsz + j0 + q * 4;
    const float4 xv0 = *(const float4*)xpt;
    const float4 xv1 = *(const float4*)(xpt + 16);

    f32x4 acc00 = (f32x4){0.f, 0.f, 0.f, 0.f};
    f32x4 acc01 = (f32x4){0.f, 0.f, 0.f, 0.f};
    f32x4 acc10 = (f32x4){0.f, 0.f, 0.f, 0.f};
    f32x4 acc11 = (f32x4){0.f, 0.f, 0.f, 0.f};

    if (t > 0) {
      const unsigned tg = (unsigned)t;
      // Poll own group's 32 producer flags (2 lanes per flag), full ballot.
      unsigned v = __hip_atomic_load(pollflag, __ATOMIC_RELAXED,
                                     __HIP_MEMORY_SCOPE_AGENT);
      while (!__all((int)(v >= tg))) {
        __builtin_amdgcn_s_sleep(1);
        v = __hip_atomic_load(pollflag, __ATOMIC_RELAXED,
                              __HIP_MEMORY_SCOPE_AGENT);
      }
      // Poll-exit: last poll load waited => ALL prior vmem retired (in-order
      // vmcnt) => outstanding == 0. Manual counts below are exact.
      const unsigned long long rb64 =
          (unsigned long long)(const char*)(grp + (size_t)(t & 1) * 16384) +
          (unsigned)cons_byte;

      uint4 hA[8], hB[8], hC[8], hD[8];
      HLOAD(hA, 0); HLOAD(hB, 1); HLOAD(hC, 2); HLOAD(hD, 3);
      asm volatile("s_waitcnt vmcnt(24)" ::: "memory");
      __builtin_amdgcn_sched_barrier(0);
      HMFMA(hA, 0);
      asm volatile("s_waitcnt vmcnt(16)" ::: "memory");
      __builtin_amdgcn_sched_barrier(0);
      HMFMA(hB, 1);
      asm volatile("s_waitcnt vmcnt(8)" ::: "memory");
      __builtin_amdgcn_sched_barrier(0);
      HMFMA(hC, 2);
      asm volatile("s_waitcnt vmcnt(0)" ::: "memory");
      __builtin_amdgcn_sched_barrier(0);
      HMFMA(hD, 3);
    }

    const f32x4 a0 = acc00 + acc01;
    const f32x4 a1 = acc10 + acc11;
    const float* xf0 = (const float*)&xv0;
    const float* xf1 = (const float*)&xv1;
    float hv0[4], hv1[4];
#pragma unroll
    for (int r = 0; r < 4; ++r) {
      hv0[r] = fast_tanh(a0[r] + xf0[r]);
      hv1[r] = fast_tanh(a1[r] + xf1[r]);
    }

    if (t == Tsz - 1) {
      *(float4*)&out[(size_t)(rb + m) * Hsz + j0 + q * 4] =
          make_float4(hv0[0], hv0[1], hv0[2], hv0[3]);
      *(float4*)&out[(size_t)(rb + m) * Hsz + j0 + 16 + q * 4] =
          make_float4(hv1[0], hv1[1], hv1[2], hv1[3]);
    } else {
      const unsigned long long s0 =
          (unsigned long long)f2bf(hv0[0])        |
          ((unsigned long long)f2bf(hv0[1]) << 16) |
          ((unsigned long long)f2bf(hv0[2]) << 32) |
          ((unsigned long long)f2bf(hv0[3]) << 48);
      const unsigned long long s1 =
          (unsigned long long)f2bf(hv1[0])        |
          ((unsigned long long)f2bf(hv1[1]) << 16) |
          ((unsigned long long)f2bf(hv1[2]) << 32) |
          ((unsigned long long)f2bf(hv1[3]) << 48);
      unsigned long long* wb = grp + (size_t)((t + 1) & 1) * 16384;
      __hip_atomic_store(wb + prod0, s0, __ATOMIC_RELAXED,
                         __HIP_MEMORY_SCOPE_AGENT);
      __hip_atomic_store(wb + prod1, s1, __ATOMIC_RELAXED,
                         __HIP_MEMORY_SCOPE_AGENT);
      // Drain own stores to the coherence point, then publish readiness.
      asm volatile("s_waitcnt vmcnt(0)" ::: "memory");
      if (lane == 0)
        __hip_atomic_store(myflag, (unsigned)(t + 1), __ATOMIC_RELAXED,
                           __HIP_MEMORY_SCOPE_AGENT);
    }
  }
}

extern "C" void kernel_launch(void* const* d_in, const int* in_sizes, int n_in,
                              void* d_out, int out_size, void* d_ws, size_t ws_size,
                              hipStream_t stream) {
  (void)in_sizes; (void)n_in; (void)out_size; (void)ws_size;
  const float* x  = (const float*)d_in[0];  // [64,512,1024]
  const float* Wh = (const float*)d_in[1];  // [1024,1024]
  const float* bh = (const float*)d_in[2];  // [1024]
  const float* Wx = (const float*)d_in[3];  // [1024,1024]
  const float* bx = (const float*)d_in[4];  // [1024]
  float* out = (float*)d_out;               // [64,1024]

  char* ws = (char*)d_ws;
  unsigned*           flags = (unsigned*)ws;                    // 8 KB used
  unsigned long long* ring  = (unsigned long long*)(ws + 65536);// 256 KB
  float*              xp    = (float*)(ws + (1 << 20));         // 128 MB

  // only flags need zeroing (step 0 reads no h buffer)
  hipMemsetAsync(d_ws, 0, 16384, stream);

  dim3 g1(Bsz * Tsz / 64, Hsz / 64);
  xp_gemm_kernel<<<g1, dim3(256), 0, stream>>>(x, Wx, bx, bh, xp);
  rnn_scan_kernel<<<dim3(128), dim3(64), 0, stream>>>(Wh, xp, out, ring, flags);
}